// Round 7
// baseline (489.527 us; speedup 1.0000x reference)
//
#include <hip/hip_runtime.h>
#include <hip/hip_bf16.h>

// Problem constants
#define BATCH 16
#define CIN 8
#define COUT 8
#define HH 512
#define WW 512
constexpr int TPX = 8;                        // pixels per thread along h (R7: 4->8 for ILP)
constexpr float EPS = 1e-5f;
constexpr float NPC = (float)BATCH * HH * WW; // per-channel element count

// MODE 0: conv -> bf16 ws + stats atomics
// MODE 1: conv -> stats atomics only (no ws write)
// MODE 2: conv recompute -> normalize -> fp32 out (reads stats)
//
// R7: TPX=8. Theory: conv = ~44us VALU content + ~53us exposed load stall
// (conserved across R0/R2/R4/R6). Per ic, a wave now has 576 FMA issue-cycles
// (vs 288) to cover its ~600-900cy load latency -> exposed stall should halve.
// VGPR budget: acc 64 + xv 30 + misc ~= 105 live, fits (256,4)'s 128 cap.
template <int MODE>
__global__ __launch_bounds__(256, 4)
void conv_kernel(const float* __restrict__ x,
                 const float* __restrict__ lin_w,
                 const float* __restrict__ gamma,
                 const float* __restrict__ beta,
                 __hip_bfloat16* __restrict__ ws_y,
                 float* __restrict__ stats,
                 float* __restrict__ out) {
    const int w  = blockIdx.x * 256 + threadIdx.x;   // 0..511
    const int h0 = blockIdx.y * TPX;                  // 0..504
    const int b  = blockIdx.z;

    float acc[TPX][COUT];
#pragma unroll
    for (int px = 0; px < TPX; ++px)
#pragma unroll
        for (int oc = 0; oc < COUT; ++oc) acc[px][oc] = 0.f;

    const float* xb = x + (size_t)b * CIN * HH * WW;
    const int wm = max(w - 1, 0), wp = min(w + 1, WW - 1);
    const bool wl = (w >= 1), wr = (w <= WW - 2);

    for (int ic = 0; ic < CIN; ++ic) {
        const float* xc = xb + (size_t)ic * HH * WW;
        float xv[TPX + 2][3];
#pragma unroll
        for (int r = 0; r < TPX + 2; ++r) {
            const int hraw = h0 - 1 + r;
            const int hcl = min(max(hraw, 0), HH - 1);
            const bool vr = (hraw >= 0) && (hraw < HH);
            const float* xr = xc + (size_t)hcl * WW;
            float a0 = xr[wm], a1 = xr[w], a2 = xr[wp];
            xv[r][0] = (vr && wl) ? a0 : 0.f;
            xv[r][1] = vr ? a1 : 0.f;
            xv[r][2] = (vr && wr) ? a2 : 0.f;
        }
#pragma unroll
        for (int kh = 0; kh < 3; ++kh) {
#pragma unroll
            for (int kw = 0; kw < 3; ++kw) {
                const int p = kh * 3 + kw;
#pragma unroll
                for (int px = 0; px < TPX; ++px) {
                    const float xval = xv[kh + px][kw];
#pragma unroll
                    for (int oc = 0; oc < COUT; ++oc) {
                        // uniform address -> s_load; SGPR operand in v_fmac
                        acc[px][oc] = fmaf(xval, lin_w[(ic * COUT + oc) * 9 + p],
                                           acc[px][oc]);
                    }
                }
            }
        }
    }

    if (MODE == 0 || MODE == 1) {
        // per-thread channel sums
        float s[COUT], q[COUT];
#pragma unroll
        for (int oc = 0; oc < COUT; ++oc) {
            float ss = 0.f, qq = 0.f;
#pragma unroll
            for (int px = 0; px < TPX; ++px) {
                ss += acc[px][oc];
                qq = fmaf(acc[px][oc], acc[px][oc], qq);
            }
            s[oc] = ss; q[oc] = qq;
        }
        // wave (64-lane) reduce
#pragma unroll
        for (int off = 32; off > 0; off >>= 1) {
#pragma unroll
            for (int oc = 0; oc < COUT; ++oc) {
                s[oc] += __shfl_down(s[oc], off);
                q[oc] += __shfl_down(q[oc], off);
            }
        }
        __shared__ float reds[4][2 * COUT];
        const int lane = threadIdx.x & 63, wv = threadIdx.x >> 6;
        if (lane == 0) {
#pragma unroll
            for (int oc = 0; oc < COUT; ++oc) {
                reds[wv][oc] = s[oc];
                reds[wv][COUT + oc] = q[oc];
            }
        }
        __syncthreads();
        if (threadIdx.x < 2 * COUT) {
            float v = reds[0][threadIdx.x] + reds[1][threadIdx.x] +
                      reds[2][threadIdx.x] + reds[3][threadIdx.x];
            atomicAdd(&stats[threadIdx.x], v);
        }
        if (MODE == 0) {
#pragma unroll
            for (int oc = 0; oc < COUT; ++oc)
#pragma unroll
                for (int px = 0; px < TPX; ++px) {
                    size_t oidx = (((size_t)(b * COUT + oc)) * HH + (h0 + px)) * WW + w;
                    ws_y[oidx] = __float2bfloat16(acc[px][oc]);
                }
        }
    } else { // MODE 2: normalize + relu + write
#pragma unroll
        for (int oc = 0; oc < COUT; ++oc) {
            const float mean = stats[oc] * (1.f / NPC);
            const float var  = stats[COUT + oc] * (1.f / NPC) - mean * mean;
            const float rstd = rsqrtf(var + EPS);
            const float sc = gamma[oc] * rstd;
            const float sh = fmaf(-mean, sc, beta[oc]);
#pragma unroll
            for (int px = 0; px < TPX; ++px) {
                size_t oidx = (((size_t)(b * COUT + oc)) * HH + (h0 + px)) * WW + w;
                out[oidx] = fmaxf(fmaf(acc[px][oc], sc, sh), 0.f);
            }
        }
    }
}

// BN+ReLU from bf16 ws, 8 elements/thread
__global__ __launch_bounds__(256)
void bn_kernel(const __hip_bfloat16* __restrict__ ws_y,
               const float* __restrict__ stats,
               const float* __restrict__ gamma,
               const float* __restrict__ beta,
               float* __restrict__ out) {
    const size_t i8 = ((size_t)blockIdx.x * 256 + threadIdx.x) * 8;
    const int oc = (int)((i8 >> 18) & 7);  // HH*WW = 2^18
    const float mean = stats[oc] * (1.f / NPC);
    const float var  = stats[COUT + oc] * (1.f / NPC) - mean * mean;
    const float rstd = rsqrtf(var + EPS);
    const float sc = gamma[oc] * rstd;
    const float sh = fmaf(-mean, sc, beta[oc]);

    const uint4 u = *(const uint4*)((const char*)ws_y + i8 * 2);
    float v[8];
    v[0] = __uint_as_float(u.x << 16);
    v[1] = __uint_as_float(u.x & 0xffff0000u);
    v[2] = __uint_as_float(u.y << 16);
    v[3] = __uint_as_float(u.y & 0xffff0000u);
    v[4] = __uint_as_float(u.z << 16);
    v[5] = __uint_as_float(u.z & 0xffff0000u);
    v[6] = __uint_as_float(u.w << 16);
    v[7] = __uint_as_float(u.w & 0xffff0000u);
    float4 o0, o1;
    o0.x = fmaxf(fmaf(v[0], sc, sh), 0.f);
    o0.y = fmaxf(fmaf(v[1], sc, sh), 0.f);
    o0.z = fmaxf(fmaf(v[2], sc, sh), 0.f);
    o0.w = fmaxf(fmaf(v[3], sc, sh), 0.f);
    o1.x = fmaxf(fmaf(v[4], sc, sh), 0.f);
    o1.y = fmaxf(fmaf(v[5], sc, sh), 0.f);
    o1.z = fmaxf(fmaf(v[6], sc, sh), 0.f);
    o1.w = fmaxf(fmaf(v[7], sc, sh), 0.f);
    *(float4*)(out + i8) = o0;
    *(float4*)(out + i8 + 4) = o1;
}

extern "C" void kernel_launch(void* const* d_in, const int* in_sizes, int n_in,
                              void* d_out, int out_size, void* d_ws, size_t ws_size,
                              hipStream_t stream) {
    const float* x     = (const float*)d_in[0];
    const float* lin_w = (const float*)d_in[1];
    // d_in[2] = lin_b: a per-channel constant shift of conv output, which
    // BatchNorm subtracts back out exactly (mean shifts identically) -> unused.
    const float* gamma = (const float*)d_in[3];
    const float* beta  = (const float*)d_in[4];
    float* out = (float*)d_out;

    float* stats = (float*)d_ws;                                  // 16 floats
    __hip_bfloat16* ws_y = (__hip_bfloat16*)((char*)d_ws + 256);  // conv output, bf16

    const size_t n_elem = (size_t)BATCH * COUT * HH * WW;         // 33,554,432
    const size_t need = 256 + n_elem * 2;

    (void)hipMemsetAsync(d_ws, 0, 256, stream);  // zero stats (ws re-poisoned 0xAA)

    dim3 grid(WW / 256, HH / TPX, BATCH);   // (2, 64, 16) = 2048 blocks
    if (ws_size >= need) {
        conv_kernel<0><<<grid, 256, 0, stream>>>(x, lin_w, gamma, beta, ws_y, stats, out);
        bn_kernel<<<(unsigned)(n_elem / (8 * 256)), 256, 0, stream>>>(ws_y, stats, gamma, beta, out);
    } else {
        conv_kernel<1><<<grid, 256, 0, stream>>>(x, lin_w, gamma, beta, ws_y, stats, out);
        conv_kernel<2><<<grid, 256, 0, stream>>>(x, lin_w, gamma, beta, ws_y, stats, out);
    }
}

// Round 8
// 443.016 us; speedup vs baseline: 1.1050x; 1.1050x over previous
//
#include <hip/hip_runtime.h>
#include <hip/hip_bf16.h>

// Problem constants
#define BATCH 16
#define CIN 8
#define COUT 8
#define HH 512
#define WW 512
constexpr int TPX = 4;                        // pixels per thread along h
constexpr float EPS = 1e-5f;
constexpr float NPC = (float)BATCH * HH * WW; // per-channel element count

constexpr int XROWS = TPX + 2;                // 6 rows staged (h0-1 .. h0+4)
constexpr int XCOLS = 258;                    // cols w0-1 .. w0+256
constexpr int XELEM = XROWS * XCOLS;          // 1548 floats per ic tile
constexpr int NSTG  = (XELEM + 255) / 256;    // 7 staging loads per thread
constexpr int NW    = CIN * 9 * COUT;         // 576 weights

typedef float f32x4_t __attribute__((ext_vector_type(4)));

// R8: double-buffered LDS staging.
// Theory: conv = ~44us VALU + ~53us lockstep-exposed stall (VALUBusy ~= one
// wave's duty at ANY occupancy, R0/R3). Fix both suspects at once:
//  H1 (x-load latency): stage x tile for ic+1 while computing ic from LDS
//  H2 (per-ic weight s_load lgkmcnt drains): weights staged to LDS once;
//     loop reads are uniform-address ds_read_b128 broadcasts (no SMEM in loop)
// Masking baked in at staging -> inner loop has zero cndmasks.
//
// MODE 0: conv -> bf16 ws + stats atomics
// MODE 1: conv -> stats atomics only (no ws write)
// MODE 2: conv recompute -> normalize -> fp32 out (reads stats)
template <int MODE>
__global__ __launch_bounds__(256, 4)
void conv_kernel(const float* __restrict__ x,
                 const float* __restrict__ lin_w,
                 const float* __restrict__ gamma,
                 const float* __restrict__ beta,
                 __hip_bfloat16* __restrict__ ws_y,
                 float* __restrict__ stats,
                 float* __restrict__ out) {
    __shared__ alignas(16) float wbuf[NW];      // [ic][p][oc]
    __shared__ float xbuf[2][XELEM];            // double-buffered x tile
    __shared__ float reds[4][2 * COUT];

    const int tid = threadIdx.x;
    const int w   = blockIdx.x * 256 + tid;     // 0..511
    const int h0  = blockIdx.y * TPX;           // 0..508
    const int b   = blockIdx.z;
    const float* xb  = x + (size_t)b * CIN * HH * WW;
    const int w0m1 = blockIdx.x * 256 - 1;      // global col of LDS c=0

    // ---- stage all 576 weights once: wbuf[ic*72 + p*8 + oc]
    for (int m = tid; m < NW; m += 256) {
        const int ic = m / 72, rem = m - ic * 72;
        const int p = rem >> 3, oc = rem & 7;
        wbuf[m] = lin_w[(ic * COUT + oc) * 9 + p];
    }

    // ---- staging helpers (linear [6][258] tile, masking baked in) ----
    float stg[NSTG];
    auto stage_load = [&](int ic) {
#pragma unroll
        for (int i = 0; i < NSTG; ++i) {
            const int m = tid + i * 256;
            if (m < XELEM) {
                const int ra = (i * 256) / XCOLS;           // folds per unrolled i
                const int rb = (i * 256 + 255) / XCOLS;
                const int r  = (ra == rb) ? ra
                              : ((m >= (ra + 1) * XCOLS) ? ra + 1 : ra);
                const int c  = m - r * XCOLS;
                const int hraw = h0 - 1 + r;
                const int wraw = w0m1 + c;
                const bool ok = (hraw >= 0) && (hraw < HH) &&
                                (wraw >= 0) && (wraw < WW);
                const int hcl = min(max(hraw, 0), HH - 1);
                const int wcl = min(max(wraw, 0), WW - 1);
                const float v = xb[(size_t)ic * (HH * WW) + (size_t)hcl * WW + wcl];
                stg[i] = ok ? v : 0.f;
            }
        }
    };
    auto stage_write = [&](int buf) {
#pragma unroll
        for (int i = 0; i < NSTG; ++i) {
            const int m = tid + i * 256;
            if (m < XELEM) xbuf[buf][m] = stg[i];
        }
    };

    float acc[TPX][COUT];
#pragma unroll
    for (int px = 0; px < TPX; ++px)
#pragma unroll
        for (int oc = 0; oc < COUT; ++oc) acc[px][oc] = 0.f;

    stage_load(0);
    stage_write(0);
    __syncthreads();

    for (int ic = 0; ic < CIN; ++ic) {
        const int cur = ic & 1;
        if (ic + 1 < CIN) stage_load(ic + 1);   // issue early: latency hides under compute

        // compute ic from LDS
        float xv[XROWS][3];
#pragma unroll
        for (int r = 0; r < XROWS; ++r)
#pragma unroll
            for (int kw = 0; kw < 3; ++kw)
                xv[r][kw] = xbuf[cur][r * XCOLS + tid + kw];  // 2-way bank alias = free

        const float* wic = &wbuf[ic * 72];
#pragma unroll
        for (int p = 0; p < 9; ++p) {
            const int kh = p / 3, kw = p - kh * 3;
            const f32x4_t wA = *(const f32x4_t*)(wic + p * 8);      // oc 0-3 broadcast
            const f32x4_t wB = *(const f32x4_t*)(wic + p * 8 + 4);  // oc 4-7
#pragma unroll
            for (int px = 0; px < TPX; ++px) {
                const float xval = xv[kh + px][kw];
                acc[px][0] = fmaf(xval, wA.x, acc[px][0]);
                acc[px][1] = fmaf(xval, wA.y, acc[px][1]);
                acc[px][2] = fmaf(xval, wA.z, acc[px][2]);
                acc[px][3] = fmaf(xval, wA.w, acc[px][3]);
                acc[px][4] = fmaf(xval, wB.x, acc[px][4]);
                acc[px][5] = fmaf(xval, wB.y, acc[px][5]);
                acc[px][6] = fmaf(xval, wB.z, acc[px][6]);
                acc[px][7] = fmaf(xval, wB.w, acc[px][7]);
            }
        }

        if (ic + 1 < CIN) {
            stage_write(cur ^ 1);               // write-late (after compute)
            __syncthreads();
        }
    }

    if (MODE == 0 || MODE == 1) {
        // per-thread channel sums
        float s[COUT], q[COUT];
#pragma unroll
        for (int oc = 0; oc < COUT; ++oc) {
            float ss = 0.f, qq = 0.f;
#pragma unroll
            for (int px = 0; px < TPX; ++px) {
                ss += acc[px][oc];
                qq = fmaf(acc[px][oc], acc[px][oc], qq);
            }
            s[oc] = ss; q[oc] = qq;
        }
        // wave (64-lane) reduce
#pragma unroll
        for (int off = 32; off > 0; off >>= 1) {
#pragma unroll
            for (int oc = 0; oc < COUT; ++oc) {
                s[oc] += __shfl_down(s[oc], off);
                q[oc] += __shfl_down(q[oc], off);
            }
        }
        const int lane = threadIdx.x & 63, wv = threadIdx.x >> 6;
        if (lane == 0) {
#pragma unroll
            for (int oc = 0; oc < COUT; ++oc) {
                reds[wv][oc] = s[oc];
                reds[wv][COUT + oc] = q[oc];
            }
        }
        __syncthreads();
        if (threadIdx.x < 2 * COUT) {
            float v = reds[0][threadIdx.x] + reds[1][threadIdx.x] +
                      reds[2][threadIdx.x] + reds[3][threadIdx.x];
            atomicAdd(&stats[threadIdx.x], v);
        }
        if (MODE == 0) {
#pragma unroll
            for (int oc = 0; oc < COUT; ++oc)
#pragma unroll
                for (int px = 0; px < TPX; ++px) {
                    size_t oidx = (((size_t)(b * COUT + oc)) * HH + (h0 + px)) * WW + w;
                    ws_y[oidx] = __float2bfloat16(acc[px][oc]);
                }
        }
    } else { // MODE 2: normalize + relu + write
#pragma unroll
        for (int oc = 0; oc < COUT; ++oc) {
            const float mean = stats[oc] * (1.f / NPC);
            const float var  = stats[COUT + oc] * (1.f / NPC) - mean * mean;
            const float rstd = rsqrtf(var + EPS);
            const float sc = gamma[oc] * rstd;
            const float sh = fmaf(-mean, sc, beta[oc]);
#pragma unroll
            for (int px = 0; px < TPX; ++px) {
                size_t oidx = (((size_t)(b * COUT + oc)) * HH + (h0 + px)) * WW + w;
                out[oidx] = fmaxf(fmaf(acc[px][oc], sc, sh), 0.f);
            }
        }
    }
}

// BN+ReLU from bf16 ws, 8 elements/thread
__global__ __launch_bounds__(256)
void bn_kernel(const __hip_bfloat16* __restrict__ ws_y,
               const float* __restrict__ stats,
               const float* __restrict__ gamma,
               const float* __restrict__ beta,
               float* __restrict__ out) {
    const size_t i8 = ((size_t)blockIdx.x * 256 + threadIdx.x) * 8;
    const int oc = (int)((i8 >> 18) & 7);  // HH*WW = 2^18
    const float mean = stats[oc] * (1.f / NPC);
    const float var  = stats[COUT + oc] * (1.f / NPC) - mean * mean;
    const float rstd = rsqrtf(var + EPS);
    const float sc = gamma[oc] * rstd;
    const float sh = fmaf(-mean, sc, beta[oc]);

    const uint4 u = *(const uint4*)((const char*)ws_y + i8 * 2);
    float v[8];
    v[0] = __uint_as_float(u.x << 16);
    v[1] = __uint_as_float(u.x & 0xffff0000u);
    v[2] = __uint_as_float(u.y << 16);
    v[3] = __uint_as_float(u.y & 0xffff0000u);
    v[4] = __uint_as_float(u.z << 16);
    v[5] = __uint_as_float(u.z & 0xffff0000u);
    v[6] = __uint_as_float(u.w << 16);
    v[7] = __uint_as_float(u.w & 0xffff0000u);
    float4 o0, o1;
    o0.x = fmaxf(fmaf(v[0], sc, sh), 0.f);
    o0.y = fmaxf(fmaf(v[1], sc, sh), 0.f);
    o0.z = fmaxf(fmaf(v[2], sc, sh), 0.f);
    o0.w = fmaxf(fmaf(v[3], sc, sh), 0.f);
    o1.x = fmaxf(fmaf(v[4], sc, sh), 0.f);
    o1.y = fmaxf(fmaf(v[5], sc, sh), 0.f);
    o1.z = fmaxf(fmaf(v[6], sc, sh), 0.f);
    o1.w = fmaxf(fmaf(v[7], sc, sh), 0.f);
    *(float4*)(out + i8) = o0;
    *(float4*)(out + i8 + 4) = o1;
}

extern "C" void kernel_launch(void* const* d_in, const int* in_sizes, int n_in,
                              void* d_out, int out_size, void* d_ws, size_t ws_size,
                              hipStream_t stream) {
    const float* x     = (const float*)d_in[0];
    const float* lin_w = (const float*)d_in[1];
    // d_in[2] = lin_b: a per-channel constant shift of conv output, which
    // BatchNorm subtracts back out exactly (mean shifts identically) -> unused.
    const float* gamma = (const float*)d_in[3];
    const float* beta  = (const float*)d_in[4];
    float* out = (float*)d_out;

    float* stats = (float*)d_ws;                                  // 16 floats
    __hip_bfloat16* ws_y = (__hip_bfloat16*)((char*)d_ws + 256);  // conv output, bf16

    const size_t n_elem = (size_t)BATCH * COUT * HH * WW;         // 33,554,432
    const size_t need = 256 + n_elem * 2;

    (void)hipMemsetAsync(d_ws, 0, 256, stream);  // zero stats (ws re-poisoned 0xAA)

    dim3 grid(WW / 256, HH / TPX, BATCH);   // (2, 128, 16) = 4096 blocks
    if (ws_size >= need) {
        conv_kernel<0><<<grid, 256, 0, stream>>>(x, lin_w, gamma, beta, ws_y, stats, out);
        bn_kernel<<<(unsigned)(n_elem / (8 * 256)), 256, 0, stream>>>(ws_y, stats, gamma, beta, out);
    } else {
        conv_kernel<1><<<grid, 256, 0, stream>>>(x, lin_w, gamma, beta, ws_y, stats, out);
        conv_kernel<2><<<grid, 256, 0, stream>>>(x, lin_w, gamma, beta, ws_y, stats, out);
    }
}